// Round 4
// baseline (1234.374 us; speedup 1.0000x reference)
//
#include <hip/hip_runtime.h>
#include <math.h>

#define T_ 16
#define B_ 32
#define S_ 256
#define H_ 256
#define E_ 300
#define V_ 1000
#define MAGIC 0x5EC0ADDEu

__device__ __forceinline__ float fast_tanh(float x) {
    return 1.0f - 2.0f / (__expf(2.0f * x) + 1.0f);
}
__device__ __forceinline__ float fast_sigm(float x) {
    return 1.0f / (1.0f + __expf(-x));
}

// ---------------------------------------------------------------------------
// Generic GEMM: C[M,N] = A[M,K](fp32, optional row-gather) @ Bw[N,K]^T + bias
// Tile 64x64, BK=32, 256 threads, 4x4 outputs/thread. M multiple of 64.
// ---------------------------------------------------------------------------
__global__ __launch_bounds__(256)
void gemm_bt(const float* __restrict__ A, const int* __restrict__ gidx, int lda,
             const float* __restrict__ Bw, const float* __restrict__ bias,
             float* __restrict__ C, int N, int K, int ldc)
{
    __shared__ float As[32][64];
    __shared__ float Bs[32][64];
    const int tid = threadIdx.x;
    const int bm = blockIdx.y * 64;
    const int bn = blockIdx.x * 64;
    const int ty = tid >> 4, tx = tid & 15;
    const int lr = tid >> 2;            // 0..63 tile row
    const int lk = (tid & 3) * 8;       // k offset within BK

    int am = bm + lr;
    int arow = gidx ? gidx[am] : am;
    const float* Ap = A + (size_t)arow * lda;
    int bnr = bn + lr;
    const float* Bp = (bnr < N) ? (Bw + (size_t)bnr * K) : nullptr;

    float acc[4][4] = {};

    for (int k0 = 0; k0 < K; k0 += 32) {
        int kb = k0 + lk;
        float av[8];
        if (kb + 8 <= K) {
            float4 p0 = *(const float4*)(Ap + kb);
            float4 p1 = *(const float4*)(Ap + kb + 4);
            av[0]=p0.x; av[1]=p0.y; av[2]=p0.z; av[3]=p0.w;
            av[4]=p1.x; av[5]=p1.y; av[6]=p1.z; av[7]=p1.w;
        } else {
            #pragma unroll
            for (int j = 0; j < 8; j++) av[j] = (kb + j < K) ? Ap[kb + j] : 0.0f;
        }
        #pragma unroll
        for (int j = 0; j < 8; j++) As[lk + j][lr] = av[j];
        if (Bp && kb + 8 <= K) {
            float4 p0 = *(const float4*)(Bp + kb);
            float4 p1 = *(const float4*)(Bp + kb + 4);
            av[0]=p0.x; av[1]=p0.y; av[2]=p0.z; av[3]=p0.w;
            av[4]=p1.x; av[5]=p1.y; av[6]=p1.z; av[7]=p1.w;
        } else if (Bp) {
            #pragma unroll
            for (int j = 0; j < 8; j++) av[j] = (kb + j < K) ? Bp[kb + j] : 0.0f;
        } else {
            #pragma unroll
            for (int j = 0; j < 8; j++) av[j] = 0.0f;
        }
        #pragma unroll
        for (int j = 0; j < 8; j++) Bs[lk + j][lr] = av[j];
        __syncthreads();
        #pragma unroll
        for (int kk = 0; kk < 32; kk++) {
            float4 a = *(const float4*)&As[kk][ty * 4];
            float4 b = *(const float4*)&Bs[kk][tx * 4];
            acc[0][0] += a.x*b.x; acc[0][1] += a.x*b.y; acc[0][2] += a.x*b.z; acc[0][3] += a.x*b.w;
            acc[1][0] += a.y*b.x; acc[1][1] += a.y*b.y; acc[1][2] += a.y*b.z; acc[1][3] += a.y*b.w;
            acc[2][0] += a.z*b.x; acc[2][1] += a.z*b.y; acc[2][2] += a.z*b.z; acc[2][3] += a.z*b.w;
            acc[3][0] += a.w*b.x; acc[3][1] += a.w*b.y; acc[3][2] += a.w*b.z; acc[3][3] += a.w*b.w;
        }
        __syncthreads();
    }
    #pragma unroll
    for (int i = 0; i < 4; i++) {
        int m = bm + ty * 4 + i;
        #pragma unroll
        for (int j = 0; j < 4; j++) {
            int n = bn + tx * 4 + j;
            if (n < N) C[(size_t)m * ldc + n] = acc[i][j] + bias[n];
        }
    }
}

// ---------------------------------------------------------------------------
// LSTM scan v2: grid = 128 blocks = (batch b, gate-quarter q). W-quarter lives
// in VGPRs (64/thread). Per step: in-register GEMV, quarters exchange gate
// pre-activations via zbuf + device-scope flags, every block redundantly
// computes the h/c update (so one sync phase per step).
// Flags: ws is poisoned 0xAA before every launch -> initial value != MAGIC.
// ---------------------------------------------------------------------------
__global__ __launch_bounds__(1024, 4)
void lstm_scan2(const float* __restrict__ xproj,   // [T,B,1024]
                const float* __restrict__ Whh,     // [1024,256]
                const float* __restrict__ bhh,     // [1024]
                const float* __restrict__ h0, const float* __restrict__ c0,
                float* __restrict__ zbuf,          // [T,B,1024]
                unsigned int* __restrict__ flags,  // [T,B,4]
                float* __restrict__ combined,      // [T,B,512] second half
                float* __restrict__ hT, float* __restrict__ cT)
{
    const int b = blockIdx.x >> 2;
    const int q = blockIdx.x & 3;
    const int tid = threadIdx.x;
    const int kq = tid >> 8;          // k-quarter 0..3 (wave-uniform)
    const int g  = tid & 255;         // gate within this W quarter
    __shared__ float hs[256], cs[256], zp[1024];

    // one-time: W rows into registers. row = q*256+g, cols kq*64 .. kq*64+63
    float w[64];
    const float* wp = Whh + ((size_t)(q * 256 + g)) * 256 + kq * 64;
    #pragma unroll
    for (int i = 0; i < 16; i++) {
        float4 v = *(const float4*)(wp + i * 4);
        w[4*i] = v.x; w[4*i+1] = v.y; w[4*i+2] = v.z; w[4*i+3] = v.w;
    }
    if (tid < 256) {
        hs[tid] = h0[b * 256 + tid];
        cs[tid] = c0[b * 256 + tid];
    }
    const float bh = bhh[q * 256 + g];
    volatile const float* vz = zbuf;   // sc0 loads: bypass L1 (cross-XCD data)
    __syncthreads();

    for (int t = 0; t < T_; t++) {
        float xp = 0.0f;
        if (tid < 256) xp = xproj[((size_t)t * B_ + b) * 1024 + q * 256 + g];

        // GEMV partial: this thread covers k = kq*64 .. kq*64+63
        const float4* h4 = (const float4*)(hs + kq * 64);  // broadcast reads
        float acc = 0.0f;
        #pragma unroll
        for (int i = 0; i < 16; i++) {
            float4 h = h4[i];
            acc += w[4*i]*h.x + w[4*i+1]*h.y + w[4*i+2]*h.z + w[4*i+3]*h.w;
        }
        zp[tid] = acc;
        __syncthreads();

        if (tid < 256) {
            float z = xp + bh + zp[g] + zp[256 + g] + zp[512 + g] + zp[768 + g];
            zbuf[((size_t)t * B_ + b) * 1024 + q * 256 + g] = z;
        }
        __threadfence();          // release: z stores device-visible
        __syncthreads();
        if (tid == 0) atomicExch(&flags[((size_t)t * B_ + b) * 4 + q], MAGIC);

        if (tid < 4) {            // wait for all 4 quarters (own is instant)
            unsigned int* f = &flags[((size_t)t * B_ + b) * 4 + tid];
            while (atomicOr(f, 0u) != MAGIC) { __builtin_amdgcn_s_sleep(2); }
        }
        __syncthreads();
        __threadfence();          // acquire

        if (tid < 256) {
            const size_t zo = ((size_t)t * B_ + b) * 1024;
            float zi  = vz[zo + tid];
            float zf  = vz[zo + 256 + tid];
            float zg  = vz[zo + 512 + tid];
            float zoo = vz[zo + 768 + tid];
            float c = fast_sigm(zf) * cs[tid] + fast_sigm(zi) * fast_tanh(zg);
            float h = fast_sigm(zoo) * fast_tanh(c);
            cs[tid] = c;
            hs[tid] = h;
            if (q == 0) {
                combined[((size_t)t * B_ + b) * 512 + 256 + tid] = h;
                if (t == T_ - 1) {
                    hT[b * 256 + tid] = h;
                    cT[b * 256 + tid] = c;
                }
            }
        }
        __syncthreads();
    }
}

// ---------------------------------------------------------------------------
// Fused attention: scores (tanh additive) + masked softmax + context.
// Block per (b,t), 256 threads.
// ---------------------------------------------------------------------------
__global__ __launch_bounds__(256)
void attn_fused(const float* __restrict__ enct,   // [S,B,H]
                const float* __restrict__ dect,   // [T,B,H]
                const float* __restrict__ enc_raw,// [S,B,H]
                const float* __restrict__ wa, const float* __restrict__ ba,
                const int* __restrict__ lens,
                float* __restrict__ ctx_out,      // [B,T,H] (d_out)
                float* __restrict__ combined)     // [T,B,512] first half
{
    const int bid = blockIdx.x;
    const int b = bid >> 4;
    const int t = bid & 15;
    const int tid = threadIdx.x;
    __shared__ float ds[256], was[256], sc[256];
    __shared__ float red[8];

    ds[tid]  = dect[((size_t)t * B_ + b) * 256 + tid];
    was[tid] = wa[tid];
    const int len = lens[b];
    const float bav = ba[0];
    __syncthreads();

    const int wv = tid >> 6, lane = tid & 63;
    for (int s = wv; s < len; s += 4) {
        const float* er = enct + ((size_t)s * B_ + b) * 256;
        float sum = 0.0f;
        #pragma unroll
        for (int j = 0; j < 4; j++) {
            int h = lane + 64 * j;
            sum += fast_tanh(er[h] + ds[h]) * was[h];
        }
        #pragma unroll
        for (int off = 32; off >= 1; off >>= 1) sum += __shfl_xor(sum, off, 64);
        if (lane == 0) sc[s] = sum + bav;
    }
    __syncthreads();

    float x = (tid < len) ? sc[tid] : -INFINITY;
    float m = x;
    #pragma unroll
    for (int off = 32; off >= 1; off >>= 1) m = fmaxf(m, __shfl_xor(m, off, 64));
    if (lane == 0) red[wv] = m;
    __syncthreads();
    m = fmaxf(fmaxf(red[0], red[1]), fmaxf(red[2], red[3]));
    float e = __expf(x - m);
    float ssum = e;
    #pragma unroll
    for (int off = 32; off >= 1; off >>= 1) ssum += __shfl_xor(ssum, off, 64);
    if (lane == 0) red[4 + wv] = ssum;
    __syncthreads();
    ssum = red[4] + red[5] + red[6] + red[7];
    __syncthreads();
    sc[tid] = e / ssum;
    __syncthreads();

    float acc = 0.0f;
    const float* eb = enc_raw + (size_t)b * 256 + tid;
    for (int s = 0; s < len; s++) acc += sc[s] * eb[(size_t)s * (B_ * H_)];
    ctx_out[((size_t)b * T_ + t) * 256 + tid] = acc;
    combined[((size_t)t * B_ + b) * 512 + tid] = acc;
}

// ---------------------------------------------------------------------------
// Vocab softmax: block per (t,b) row, 256 threads x 4 elems (V=1000).
// ---------------------------------------------------------------------------
__global__ __launch_bounds__(256)
void vocab_softmax(const float* __restrict__ logits, float* __restrict__ probs)
{
    const int r = blockIdx.x;
    const int tid = threadIdx.x;
    const int wv = tid >> 6, lane = tid & 63;
    __shared__ float red[8];
    const float* row = logits + (size_t)r * V_;
    float v[4];
    float mx = -INFINITY;
    #pragma unroll
    for (int j = 0; j < 4; j++) {
        int idx = tid + 256 * j;
        v[j] = (idx < V_) ? row[idx] : -INFINITY;
        mx = fmaxf(mx, v[j]);
    }
    #pragma unroll
    for (int off = 32; off >= 1; off >>= 1) mx = fmaxf(mx, __shfl_xor(mx, off, 64));
    if (lane == 0) red[wv] = mx;
    __syncthreads();
    mx = fmaxf(fmaxf(red[0], red[1]), fmaxf(red[2], red[3]));
    float s = 0.0f;
    #pragma unroll
    for (int j = 0; j < 4; j++) {
        v[j] = __expf(v[j] - mx);
        s += v[j];
    }
    #pragma unroll
    for (int off = 32; off >= 1; off >>= 1) s += __shfl_xor(s, off, 64);
    if (lane == 0) red[4 + wv] = s;
    __syncthreads();
    s = red[4] + red[5] + red[6] + red[7];
    float inv = 1.0f / s;
    #pragma unroll
    for (int j = 0; j < 4; j++) {
        int idx = tid + 256 * j;
        if (idx < V_) probs[(size_t)r * V_ + idx] = v[j] * inv;
    }
}

extern "C" void kernel_launch(void* const* d_in, const int* in_sizes, int n_in,
                              void* d_out, int out_size, void* d_ws, size_t ws_size,
                              hipStream_t stream) {
    const int*   tv       = (const int*)d_in[0];     // [T,B]
    const float* h0       = (const float*)d_in[1];   // [1,B,H]
    const float* c0       = (const float*)d_in[2];
    const float* enc_raw  = (const float*)d_in[3];   // [S,B,H]
    const int*   lens     = (const int*)d_in[4];     // [B]
    const float* emb      = (const float*)d_in[5];   // [V,E]
    const float* W_ih     = (const float*)d_in[6];   // [4H,E]
    const float* W_hh     = (const float*)d_in[7];   // [4H,H]
    const float* b_ih     = (const float*)d_in[8];
    const float* b_hh     = (const float*)d_in[9];
    const float* We       = (const float*)d_in[10];  // [H,H]
    const float* be       = (const float*)d_in[11];
    const float* Wd       = (const float*)d_in[12];
    const float* bd       = (const float*)d_in[13];
    const float* wa       = (const float*)d_in[14];  // [H]
    const float* ba       = (const float*)d_in[15];  // [1]
    const float* W_out    = (const float*)d_in[16];  // [V,2H]
    const float* b_out    = (const float*)d_in[17];

    // workspace layout (fp32; 14.12 MB total, ~= round-3's proven footprint)
    float* ws       = (float*)d_ws;
    float* enct     = ws;                       // [S*B,256]   2,097,152
    float* xproj    = ws + 2097152;             // [T*B,1024]    524,288
    float* dect     = ws + 2621440;             // [T*B,256]     131,072
    float* logits   = ws + 2752512;             // [T*B,1000]    512,000
    float* combined = ws + 3264512;             // [T*B,512]     262,144
    // zbuf overlaps dect+logits: zbuf live only during lstm_scan2 (step 3);
    // dect is written in step 4, logits in step 6 — disjoint lifetimes.
    float* zbuf     = ws + 2621440;             // [T,B,1024]    524,288
    unsigned int* flags = (unsigned int*)(ws + 3526656); // [T,B,4] = 2048

    // d_out layout (fp32): probs [T,B,V], hT [1,B,H], cT [1,B,H], ctx [B,T,H]
    float* out      = (float*)d_out;
    float* probs    = out;
    float* hT       = out + 512000;
    float* cT       = out + 520192;
    float* ctx_out  = out + 528384;

    // 1) x_proj = gather(emb, tv) @ W_ih^T + b_ih  -> [T*B, 1024]
    {
        dim3 grid(1024 / 64, 512 / 64);
        gemm_bt<<<grid, 256, 0, stream>>>(emb, tv, E_, W_ih, b_ih, xproj, 1024, E_, 1024);
    }
    // 2) enc_t = enc_raw @ We^T + be  -> [S*B, 256]
    {
        dim3 grid(256 / 64, 8192 / 64);
        gemm_bt<<<grid, 256, 0, stream>>>(enc_raw, nullptr, H_, We, be, enct, 256, H_, 256);
    }
    // 3) LSTM scan (128 blocks = 32 batches x 4 gate-quarters)
    lstm_scan2<<<128, 1024, 0, stream>>>(xproj, W_hh, b_hh, h0, c0,
                                         zbuf, flags, combined, hT, cT);
    // 4) dec_t = output @ Wd^T + bd  -> [T*B, 256]
    {
        dim3 grid(256 / 64, 512 / 64);
        gemm_bt<<<grid, 256, 0, stream>>>(combined + 256, nullptr, 512, Wd, bd, dect, 256, H_, 256);
    }
    // 5) fused attention -> context
    attn_fused<<<512, 256, 0, stream>>>(enct, dect, enc_raw, wa, ba, lens, ctx_out, combined);
    // 6) logits = combined @ W_out^T + b_out -> [T*B, 1000]
    {
        dim3 grid((1000 + 63) / 64, 512 / 64);
        gemm_bt<<<grid, 256, 0, stream>>>(combined, nullptr, 512, W_out, b_out, logits, V_, 512, V_);
    }
    // 7) vocab softmax -> probs
    vocab_softmax<<<512, 256, 0, stream>>>(logits, probs);
}

// Round 5
// 392.384 us; speedup vs baseline: 3.1458x; 3.1458x over previous
//
#include <hip/hip_runtime.h>
#include <math.h>

typedef unsigned int u32;
typedef unsigned short u16;

#define T_ 16
#define B_ 32
#define S_ 256
#define H_ 256
#define E_ 300
#define V_ 1000

__device__ __forceinline__ float fast_tanh(float x) {
    return 1.0f - 2.0f / (__expf(2.0f * x) + 1.0f);
}
__device__ __forceinline__ float fast_sigm(float x) {
    return 1.0f / (1.0f + __expf(-x));
}
__device__ __forceinline__ float bf2f(u16 x) { return __uint_as_float(((u32)x) << 16); }
__device__ __forceinline__ u16 f2bf(float f) {
    u32 u = __float_as_uint(f);
    u32 r = (u + 0x7fffu + ((u >> 16) & 1u)) >> 16;
    return (u16)r;
}

// ---------------------------------------------------------------------------
// Generic GEMM: C[M,N] = A[M,K](fp32, optional row-gather) @ Bw[N,K]^T + bias
// Tile 64x64, BK=32, 256 threads, 4x4 outputs/thread. M multiple of 64.
// ---------------------------------------------------------------------------
__global__ __launch_bounds__(256)
void gemm_bt(const float* __restrict__ A, const int* __restrict__ gidx, int lda,
             const float* __restrict__ Bw, const float* __restrict__ bias,
             float* __restrict__ C, int N, int K, int ldc)
{
    __shared__ float As[32][64];
    __shared__ float Bs[32][64];
    const int tid = threadIdx.x;
    const int bm = blockIdx.y * 64;
    const int bn = blockIdx.x * 64;
    const int ty = tid >> 4, tx = tid & 15;
    const int lr = tid >> 2;            // 0..63 tile row
    const int lk = (tid & 3) * 8;       // k offset within BK

    int am = bm + lr;
    int arow = gidx ? gidx[am] : am;
    const float* Ap = A + (size_t)arow * lda;
    int bnr = bn + lr;
    const float* Bp = (bnr < N) ? (Bw + (size_t)bnr * K) : nullptr;

    float acc[4][4] = {};

    for (int k0 = 0; k0 < K; k0 += 32) {
        int kb = k0 + lk;
        float av[8];
        if (kb + 8 <= K) {
            float4 p0 = *(const float4*)(Ap + kb);
            float4 p1 = *(const float4*)(Ap + kb + 4);
            av[0]=p0.x; av[1]=p0.y; av[2]=p0.z; av[3]=p0.w;
            av[4]=p1.x; av[5]=p1.y; av[6]=p1.z; av[7]=p1.w;
        } else {
            #pragma unroll
            for (int j = 0; j < 8; j++) av[j] = (kb + j < K) ? Ap[kb + j] : 0.0f;
        }
        #pragma unroll
        for (int j = 0; j < 8; j++) As[lk + j][lr] = av[j];
        if (Bp && kb + 8 <= K) {
            float4 p0 = *(const float4*)(Bp + kb);
            float4 p1 = *(const float4*)(Bp + kb + 4);
            av[0]=p0.x; av[1]=p0.y; av[2]=p0.z; av[3]=p0.w;
            av[4]=p1.x; av[5]=p1.y; av[6]=p1.z; av[7]=p1.w;
        } else if (Bp) {
            #pragma unroll
            for (int j = 0; j < 8; j++) av[j] = (kb + j < K) ? Bp[kb + j] : 0.0f;
        } else {
            #pragma unroll
            for (int j = 0; j < 8; j++) av[j] = 0.0f;
        }
        #pragma unroll
        for (int j = 0; j < 8; j++) Bs[lk + j][lr] = av[j];
        __syncthreads();
        #pragma unroll
        for (int kk = 0; kk < 32; kk++) {
            float4 a = *(const float4*)&As[kk][ty * 4];
            float4 b = *(const float4*)&Bs[kk][tx * 4];
            acc[0][0] += a.x*b.x; acc[0][1] += a.x*b.y; acc[0][2] += a.x*b.z; acc[0][3] += a.x*b.w;
            acc[1][0] += a.y*b.x; acc[1][1] += a.y*b.y; acc[1][2] += a.y*b.z; acc[1][3] += a.y*b.w;
            acc[2][0] += a.z*b.x; acc[2][1] += a.z*b.y; acc[2][2] += a.z*b.z; acc[2][3] += a.z*b.w;
            acc[3][0] += a.w*b.x; acc[3][1] += a.w*b.y; acc[3][2] += a.w*b.z; acc[3][3] += a.w*b.w;
        }
        __syncthreads();
    }
    #pragma unroll
    for (int i = 0; i < 4; i++) {
        int m = bm + ty * 4 + i;
        #pragma unroll
        for (int j = 0; j < 4; j++) {
            int n = bn + tx * 4 + j;
            if (n < N) C[(size_t)m * ldc + n] = acc[i][j] + bias[n];
        }
    }
}

// ---------------------------------------------------------------------------
// One-time transpose: Wt[k][r] = bf16(W_hh[r][k]).  idx = k*1024 + r.
// Writes fully coalesced; reads are strided but total only ~256K line-reqs
// spread over the whole device (L2-cached after first touch) — ~3 us.
// ---------------------------------------------------------------------------
__global__ __launch_bounds__(256)
void transpose_whh(const float* __restrict__ Whh, u16* __restrict__ Wt)
{
    int idx = blockIdx.x * 256 + threadIdx.x;      // 0 .. 262143
    int k = idx >> 10;
    int r = idx & 1023;
    Wt[idx] = f2bf(Whh[(size_t)r * 256 + k]);
}

// ---------------------------------------------------------------------------
// LSTM scan v3: 32 blocks (one per batch), 1024 threads (one per gate row).
// W_hh transposed+bf16 in workspace: thread r reads Wt[k*1024+r] — contiguous
// lane addresses (dense 128B/wave, no address divergence, the round-3 killer).
// h[k] broadcast from LDS. No cross-block communication (round-4 killer).
// ---------------------------------------------------------------------------
__global__ __launch_bounds__(1024)
void lstm_scan3(const float* __restrict__ xproj,   // [T,B,1024]
                const u16*   __restrict__ Wt,      // [256,1024] bf16
                const float* __restrict__ bhh,     // [1024]
                const float* __restrict__ h0, const float* __restrict__ c0,
                float* __restrict__ combined,      // [T,B,512] second half
                float* __restrict__ hT, float* __restrict__ cT)
{
    const int b = blockIdx.x;
    const int r = threadIdx.x;          // gate row 0..1023
    __shared__ float hs[256], cs[256], zp[1024];
    if (r < 256) {
        hs[r] = h0[b * 256 + r];
        cs[r] = c0[b * 256 + r];
    }
    const float bh = bhh[r];
    __syncthreads();

    for (int t = 0; t < T_; t++) {
        float acc = xproj[((size_t)t * B_ + b) * 1024 + r] + bh;
        const u16* wp = Wt + r;
        #pragma unroll 8
        for (int k = 0; k < 256; k += 4) {
            float4 h = *(const float4*)&hs[k];     // LDS broadcast (free)
            acc += bf2f(wp[(size_t)(k + 0) * 1024]) * h.x
                 + bf2f(wp[(size_t)(k + 1) * 1024]) * h.y
                 + bf2f(wp[(size_t)(k + 2) * 1024]) * h.z
                 + bf2f(wp[(size_t)(k + 3) * 1024]) * h.w;
        }
        zp[r] = acc;
        __syncthreads();
        if (r < 256) {
            float ig = fast_sigm(zp[r]);
            float fg = fast_sigm(zp[256 + r]);
            float gg = fast_tanh(zp[512 + r]);
            float og = fast_sigm(zp[768 + r]);
            float c = fg * cs[r] + ig * gg;
            float h = og * fast_tanh(c);
            cs[r] = c;
            hs[r] = h;
            combined[((size_t)t * B_ + b) * 512 + 256 + r] = h;
            if (t == T_ - 1) {
                hT[b * 256 + r] = h;
                cT[b * 256 + r] = c;
            }
        }
        __syncthreads();
    }
}

// ---------------------------------------------------------------------------
// Fused attention: scores (tanh additive) + masked softmax + context.
// Block per (b,t), 256 threads.
// ---------------------------------------------------------------------------
__global__ __launch_bounds__(256)
void attn_fused(const float* __restrict__ enct,   // [S,B,H]
                const float* __restrict__ dect,   // [T,B,H]
                const float* __restrict__ enc_raw,// [S,B,H]
                const float* __restrict__ wa, const float* __restrict__ ba,
                const int* __restrict__ lens,
                float* __restrict__ ctx_out,      // [B,T,H] (d_out)
                float* __restrict__ combined)     // [T,B,512] first half
{
    const int bid = blockIdx.x;
    const int b = bid >> 4;
    const int t = bid & 15;
    const int tid = threadIdx.x;
    __shared__ float ds[256], was[256], sc[256];
    __shared__ float red[8];

    ds[tid]  = dect[((size_t)t * B_ + b) * 256 + tid];
    was[tid] = wa[tid];
    const int len = lens[b];
    const float bav = ba[0];
    __syncthreads();

    const int wv = tid >> 6, lane = tid & 63;
    for (int s = wv; s < len; s += 4) {
        const float* er = enct + ((size_t)s * B_ + b) * 256;
        float sum = 0.0f;
        #pragma unroll
        for (int j = 0; j < 4; j++) {
            int h = lane + 64 * j;
            sum += fast_tanh(er[h] + ds[h]) * was[h];
        }
        #pragma unroll
        for (int off = 32; off >= 1; off >>= 1) sum += __shfl_xor(sum, off, 64);
        if (lane == 0) sc[s] = sum + bav;
    }
    __syncthreads();

    float x = (tid < len) ? sc[tid] : -INFINITY;
    float m = x;
    #pragma unroll
    for (int off = 32; off >= 1; off >>= 1) m = fmaxf(m, __shfl_xor(m, off, 64));
    if (lane == 0) red[wv] = m;
    __syncthreads();
    m = fmaxf(fmaxf(red[0], red[1]), fmaxf(red[2], red[3]));
    float e = __expf(x - m);
    float ssum = e;
    #pragma unroll
    for (int off = 32; off >= 1; off >>= 1) ssum += __shfl_xor(ssum, off, 64);
    if (lane == 0) red[4 + wv] = ssum;
    __syncthreads();
    ssum = red[4] + red[5] + red[6] + red[7];
    __syncthreads();
    sc[tid] = e / ssum;
    __syncthreads();

    float acc = 0.0f;
    const float* eb = enc_raw + (size_t)b * 256 + tid;
    for (int s = 0; s < len; s++) acc += sc[s] * eb[(size_t)s * (B_ * H_)];
    ctx_out[((size_t)b * T_ + t) * 256 + tid] = acc;
    combined[((size_t)t * B_ + b) * 512 + tid] = acc;
}

// ---------------------------------------------------------------------------
// Vocab softmax: block per (t,b) row, 256 threads x 4 elems (V=1000).
// ---------------------------------------------------------------------------
__global__ __launch_bounds__(256)
void vocab_softmax(const float* __restrict__ logits, float* __restrict__ probs)
{
    const int r = blockIdx.x;
    const int tid = threadIdx.x;
    const int wv = tid >> 6, lane = tid & 63;
    __shared__ float red[8];
    const float* row = logits + (size_t)r * V_;
    float v[4];
    float mx = -INFINITY;
    #pragma unroll
    for (int j = 0; j < 4; j++) {
        int idx = tid + 256 * j;
        v[j] = (idx < V_) ? row[idx] : -INFINITY;
        mx = fmaxf(mx, v[j]);
    }
    #pragma unroll
    for (int off = 32; off >= 1; off >>= 1) mx = fmaxf(mx, __shfl_xor(mx, off, 64));
    if (lane == 0) red[wv] = mx;
    __syncthreads();
    mx = fmaxf(fmaxf(red[0], red[1]), fmaxf(red[2], red[3]));
    float s = 0.0f;
    #pragma unroll
    for (int j = 0; j < 4; j++) {
        v[j] = __expf(v[j] - mx);
        s += v[j];
    }
    #pragma unroll
    for (int off = 32; off >= 1; off >>= 1) s += __shfl_xor(s, off, 64);
    if (lane == 0) red[4 + wv] = s;
    __syncthreads();
    s = red[4] + red[5] + red[6] + red[7];
    float inv = 1.0f / s;
    #pragma unroll
    for (int j = 0; j < 4; j++) {
        int idx = tid + 256 * j;
        if (idx < V_) probs[(size_t)r * V_ + idx] = v[j] * inv;
    }
}

extern "C" void kernel_launch(void* const* d_in, const int* in_sizes, int n_in,
                              void* d_out, int out_size, void* d_ws, size_t ws_size,
                              hipStream_t stream) {
    const int*   tv       = (const int*)d_in[0];     // [T,B]
    const float* h0       = (const float*)d_in[1];   // [1,B,H]
    const float* c0       = (const float*)d_in[2];
    const float* enc_raw  = (const float*)d_in[3];   // [S,B,H]
    const int*   lens     = (const int*)d_in[4];     // [B]
    const float* emb      = (const float*)d_in[5];   // [V,E]
    const float* W_ih     = (const float*)d_in[6];   // [4H,E]
    const float* W_hh     = (const float*)d_in[7];   // [4H,H]
    const float* b_ih     = (const float*)d_in[8];
    const float* b_hh     = (const float*)d_in[9];
    const float* We       = (const float*)d_in[10];  // [H,H]
    const float* be       = (const float*)d_in[11];
    const float* Wd       = (const float*)d_in[12];
    const float* bd       = (const float*)d_in[13];
    const float* wa       = (const float*)d_in[14];  // [H]
    const float* ba       = (const float*)d_in[15];  // [1]
    const float* W_out    = (const float*)d_in[16];  // [V,2H]
    const float* b_out    = (const float*)d_in[17];

    // workspace layout (fp32 words; 14.6 MB total)
    float* ws       = (float*)d_ws;
    float* enct     = ws;                       // [S*B,256]   2,097,152
    float* xproj    = ws + 2097152;             // [T*B,1024]    524,288
    float* dect     = ws + 2621440;             // [T*B,256]     131,072
    float* logits   = ws + 2752512;             // [T*B,1000]    512,000
    float* combined = ws + 3264512;             // [T*B,512]     262,144
    u16*   Wt       = (u16*)(ws + 3526656);     // [256,1024] bf16 = 262,144 u16

    // d_out layout (fp32): probs [T,B,V], hT [1,B,H], cT [1,B,H], ctx [B,T,H]
    float* out      = (float*)d_out;
    float* probs    = out;
    float* hT       = out + 512000;
    float* cT       = out + 520192;
    float* ctx_out  = out + 528384;

    // 0) transpose W_hh -> Wt (bf16, [k][r])
    transpose_whh<<<1024, 256, 0, stream>>>(W_hh, Wt);
    // 1) x_proj = gather(emb, tv) @ W_ih^T + b_ih  -> [T*B, 1024]
    {
        dim3 grid(1024 / 64, 512 / 64);
        gemm_bt<<<grid, 256, 0, stream>>>(emb, tv, E_, W_ih, b_ih, xproj, 1024, E_, 1024);
    }
    // 2) enc_t = enc_raw @ We^T + be  -> [S*B, 256]
    {
        dim3 grid(256 / 64, 8192 / 64);
        gemm_bt<<<grid, 256, 0, stream>>>(enc_raw, nullptr, H_, We, be, enct, 256, H_, 256);
    }
    // 3) LSTM scan (32 blocks, coalesced bf16 Wt, no cross-block comm)
    lstm_scan3<<<32, 1024, 0, stream>>>(xproj, Wt, b_hh, h0, c0, combined, hT, cT);
    // 4) dec_t = output @ Wd^T + bd  -> [T*B, 256]
    {
        dim3 grid(256 / 64, 512 / 64);
        gemm_bt<<<grid, 256, 0, stream>>>(combined + 256, nullptr, 512, Wd, bd, dect, 256, H_, 256);
    }
    // 5) fused attention -> context
    attn_fused<<<512, 256, 0, stream>>>(enct, dect, enc_raw, wa, ba, lens, ctx_out, combined);
    // 6) logits = combined @ W_out^T + b_out -> [T*B, 1000]
    {
        dim3 grid((1000 + 63) / 64, 512 / 64);
        gemm_bt<<<grid, 256, 0, stream>>>(combined, nullptr, 512, W_out, b_out, logits, V_, 512, V_);
    }
    // 7) vocab softmax -> probs
    vocab_softmax<<<512, 256, 0, stream>>>(logits, probs);
}